// Round 1
// baseline (2884.430 us; speedup 1.0000x reference)
//
#include <hip/hip_runtime.h>
#include <math.h>

#define WD 80
#define HW 6400
#define CH 64
#define IMG (CH*HW)      // 409600 floats per image
#define NIMG 8           // B*L
#define NPAIR 32         // B*L*L

// ---------------- transformation matrices (inverse affine) ----------------
__global__ void prep_mats(const float* __restrict__ P, float* __restrict__ mats) {
    int p = threadIdx.x;
    if (p >= NPAIR) return;
    const float* m = P + p * 16;           // (4,4) row-major
    float m00 = m[0], m01 = m[1], m02 = m[3] / 0.8f;
    float m10 = m[4], m11 = m[5], m12 = m[7] / 0.8f;
    float cx = 40.0f, cy = 40.0f;
    float tx = cx - (m00 * cx + m01 * cy) + m02;
    float ty = cy - (m10 * cx + m11 * cy) + m12;
    float det = m00 * m11 - m01 * m10;
    float id = 1.0f / det;
    float a00 =  m11 * id, a01 = -m01 * id;
    float a10 = -m10 * id, a11 =  m00 * id;
    float a02 = -(a00 * tx + a01 * ty);
    float a12 = -(a10 * tx + a11 * ty);
    float* o = mats + p * 6;
    o[0] = a00; o[1] = a01; o[2] = a02;
    o[3] = a10; o[4] = a11; o[5] = a12;
}

// ---------------- nearest-neighbor validity mask ----------------
__global__ void make_mask(const float* __restrict__ mats, float* __restrict__ mask) {
    int p = blockIdx.x;
    const float* a = mats + p * 6;
    float a0 = a[0], a1 = a[1], a2 = a[2], a3 = a[3], a4 = a[4], a5 = a[5];
    for (int q = threadIdx.x; q < HW; q += blockDim.x) {
        float x = (float)(q % WD), y = (float)(q / WD);
        float sx = a0 * x + a1 * y + a2;
        float sy = a3 * x + a4 * y + a5;
        int ix = (int)rintf(sx), iy = (int)rintf(sy);   // round half-to-even, matches jnp.round
        mask[p * HW + q] = (ix >= 0 && ix < WD && iy >= 0 && iy < WD) ? 1.0f : 0.0f;
    }
}

// ---------------- initial rotation: y[.,c,a,b] = x[.,c,79-b,a] ----------------
__global__ void rot_init(const float* __restrict__ x, float* __restrict__ y) {
    int t = blockIdx.x * blockDim.x + threadIdx.x;
    if (t >= NIMG * IMG) return;
    int bb = t % WD;
    int a  = (t / WD) % WD;
    int c  = t / HW;                // combined img*CH + channel
    y[t] = x[c * HW + (WD - 1 - bb) * WD + a];
}

// ---------------- generic direct 3x3 conv (SAME, zero pad) ----------------
// grid (5,5,nimg*4), block 256.  Computes 16 out-channels (co-group = blockIdx.z&3).
// in1 != null -> 128 input channels split across two buffers [in0 | in1].
// act: 0=none, 1=sigmoid, 2=tanh.  mulb: elementwise multiply after activation.
template<int CO_STRIDE>
__global__ __launch_bounds__(256)
void conv_gen(const float* __restrict__ in0,
              const float* __restrict__ in1,
              const float* __restrict__ w,      // pre-offset to (co_group0, cin0)
              const float* __restrict__ bias,   // nullable (16*cog+co indexing)
              const float* __restrict__ mulb,   // nullable
              float* __restrict__ out,
              int act) {
    __shared__ float lds[16][324];
    int tx0 = blockIdx.x * 16, ty0 = blockIdx.y * 16;
    int img = blockIdx.z >> 2;
    int cog = blockIdx.z & 3;
    int px = threadIdx.x & 15, py = threadIdx.x >> 4;
    float acc[16];
#pragma unroll
    for (int i = 0; i < 16; ++i) acc[i] = 0.f;
    const int nchunk = (in1 != nullptr) ? 8 : 4;
    for (int ch = 0; ch < nchunk; ++ch) {
        const float* src = (ch < 4 ? in0 : in1) + (size_t)img * IMG + (size_t)(ch & 3) * 16 * HW;
        for (int idx = threadIdx.x; idx < 324 * 16; idx += 256) {
            int c = idx / 324, pos = idx % 324;
            int gy = ty0 - 1 + pos / 18, gx = tx0 - 1 + pos % 18;
            float v = 0.f;
            if (gx >= 0 && gx < WD && gy >= 0 && gy < WD) v = src[c * HW + gy * WD + gx];
            lds[c][pos] = v;
        }
        __syncthreads();
        int cc = ch * 16;
        const float* wb = w + cog * 16 * CO_STRIDE + cc * 9;
        int posb = py * 18 + px;
        for (int cin = 0; cin < 16; ++cin) {
            const float* wr = wb + cin * 9;
#pragma unroll
            for (int ky = 0; ky < 3; ++ky)
#pragma unroll
            for (int kx = 0; kx < 3; ++kx) {
                float v = lds[cin][posb + ky * 18 + kx];
                int tap = ky * 3 + kx;
#pragma unroll
                for (int co = 0; co < 16; ++co)
                    acc[co] += v * wr[co * CO_STRIDE + tap];
            }
        }
        __syncthreads();
    }
    size_t obase = (size_t)img * IMG + (size_t)(cog * 16) * HW + (size_t)(ty0 + py) * WD + tx0 + px;
#pragma unroll
    for (int co = 0; co < 16; ++co) {
        float r = acc[co];
        if (bias) r += bias[cog * 16 + co];
        if (act == 1) r = 1.f / (1.f + expf(-r));
        else if (act == 2) r = tanhf(r);
        if (mulb) r *= mulb[obase + (size_t)co * HW];
        out[obase + (size_t)co * HW] = r;
    }
}

// ---------------- fused: bilinear warp + conv_n + mask + mean over senders ----------------
// grid (5,5,NIMG*4): bj = blockIdx.z>>2 (target b*L+j), co-group = blockIdx.z&3
__global__ __launch_bounds__(256)
void msg_fused(const float* __restrict__ y,
               const float* __restrict__ ego,   // conv_e(y[b,j]) + msg_b
               const float* __restrict__ mats,
               const float* __restrict__ mask,
               const float* __restrict__ w,     // msg_w base (co0, cin0)
               float* __restrict__ agg) {
    __shared__ float lds[16][324];
    __shared__ int anyflag;
    int tx0 = blockIdx.x * 16, ty0 = blockIdx.y * 16;
    int bj = blockIdx.z >> 2;
    int b = bj >> 2, j = bj & 3;
    int cog = blockIdx.z & 3;
    int px = threadIdx.x & 15, py = threadIdx.x >> 4;
    float acc[16];
#pragma unroll
    for (int i = 0; i < 16; ++i) acc[i] = 0.f;
    float msum = 0.f;
    int posb = py * 18 + px;

    for (int i = 0; i < 4; ++i) {
        int p = (b * 4 + i) * 4 + j;
        float m = mask[(size_t)p * HW + (ty0 + py) * WD + tx0 + px];
        if (threadIdx.x == 0) anyflag = 0;
        __syncthreads();
        if (m != 0.f) anyflag = 1;
        __syncthreads();
        if (!anyflag) continue;      // block-uniform skip
        msum += m;

        // precompute this thread's staging taps (up to 2 halo positions)
        const float* a = mats + p * 6;
        float a0 = a[0], a1 = a[1], a2 = a[2], a3 = a[3], a4 = a[4], a5 = a[5];
        int   cidx[2][4];
        float cw[2][4];
#pragma unroll
        for (int s = 0; s < 2; ++s) {
#pragma unroll
            for (int k = 0; k < 4; ++k) { cidx[s][k] = 0; cw[s][k] = 0.f; }
            int pos = threadIdx.x + s * 256;
            if (pos < 324) {
                int gy = ty0 - 1 + pos / 18, gx = tx0 - 1 + pos % 18;
                if (gx >= 0 && gx < WD && gy >= 0 && gy < WD) {   // SAME zero-pad outside
                    float sx = a0 * gx + a1 * gy + a2;
                    float sy = a3 * gx + a4 * gy + a5;
                    float flx = floorf(sx), fly = floorf(sy);
                    float fx = sx - flx, fy = sy - fly;
                    int x0 = (int)flx, y0 = (int)fly;
                    float wt[4] = { (1.f - fx) * (1.f - fy), fx * (1.f - fy),
                                    (1.f - fx) * fy,          fx * fy };
                    int xs[4] = { x0, x0 + 1, x0, x0 + 1 };
                    int ys[4] = { y0, y0, y0 + 1, y0 + 1 };
#pragma unroll
                    for (int k = 0; k < 4; ++k) {
                        bool valid = xs[k] >= 0 && xs[k] < WD && ys[k] >= 0 && ys[k] < WD;
                        int cx = min(max(xs[k], 0), WD - 1);
                        int cy = min(max(ys[k], 0), WD - 1);
                        cidx[s][k] = cy * WD + cx;
                        cw[s][k] = valid ? wt[k] : 0.f;
                    }
                }
            }
        }

        const float* src = y + (size_t)(b * 4 + i) * IMG;
        for (int ch = 0; ch < 4; ++ch) {
            const float* sc = src + (size_t)ch * 16 * HW;
#pragma unroll
            for (int s = 0; s < 2; ++s) {
                int pos = threadIdx.x + s * 256;
                if (pos < 324) {
                    for (int c = 0; c < 16; ++c) {
                        const float* scc = sc + c * HW;
                        float v = cw[s][0] * scc[cidx[s][0]] + cw[s][1] * scc[cidx[s][1]]
                                + cw[s][2] * scc[cidx[s][2]] + cw[s][3] * scc[cidx[s][3]];
                        lds[c][pos] = v;
                    }
                }
            }
            __syncthreads();
            int cc = ch * 16;
            const float* wb = w + cog * 16 * 1152 + cc * 9;
            for (int cin = 0; cin < 16; ++cin) {
                const float* wr = wb + cin * 9;
#pragma unroll
                for (int ky = 0; ky < 3; ++ky)
#pragma unroll
                for (int kx = 0; kx < 3; ++kx) {
                    float v = lds[cin][posb + ky * 18 + kx] * m;
                    int tap = ky * 3 + kx;
#pragma unroll
                    for (int co = 0; co < 16; ++co)
                        acc[co] += v * wr[co * 1152 + tap];
                }
            }
            __syncthreads();
        }
    }

    size_t obase = (size_t)bj * IMG + (size_t)(cog * 16) * HW + (size_t)(ty0 + py) * WD + tx0 + px;
#pragma unroll
    for (int co = 0; co < 16; ++co) {
        float r = acc[co] + msum * ego[obase + (size_t)co * HW];
        agg[obase + (size_t)co * HW] = r * 0.25f;
    }
}

// ---------------- final: out[b,h,w,o] = sum_c h1[b*L, c, w, 79-h] * mlp_w[o,c] + mlp_b[o] ----------------
__global__ void final_mlp(const float* __restrict__ yfin, const float* __restrict__ mw,
                          const float* __restrict__ mb, float* __restrict__ out) {
    int t = blockIdx.x * blockDim.x + threadIdx.x;
    if (t >= 2 * HW * CH) return;
    int o  = t & 63;
    int wv = (t >> 6) % WD;
    int h  = ((t >> 6) / WD) % WD;
    int b  = t / (CH * HW);
    const float* src = yfin + (size_t)(b * 4) * IMG + wv * WD + (WD - 1 - h);
    float r = mb[o];
#pragma unroll 8
    for (int c = 0; c < CH; ++c) r += src[(size_t)c * HW] * mw[o * CH + c];
    out[t] = r;
}

extern "C" void kernel_launch(void* const* d_in, const int* in_sizes, int n_in,
                              void* d_out, int out_size, void* d_ws, size_t ws_size,
                              hipStream_t stream) {
    const float* x       = (const float*)d_in[0];
    const float* P       = (const float*)d_in[2];
    const float* msg_w   = (const float*)d_in[4];
    const float* msg_b   = (const float*)d_in[5];
    const float* gates_w = (const float*)d_in[6];
    const float* gates_b = (const float*)d_in[7];
    const float* can_w   = (const float*)d_in[8];
    const float* can_b   = (const float*)d_in[9];
    const float* mlp_w   = (const float*)d_in[10];
    const float* mlp_b   = (const float*)d_in[11];
    float* out = (float*)d_out;

    float* ws   = (float*)d_ws;
    float* mats = ws;                       // 192
    float* mask = ws + 256;                 // 204800
    float* Y0   = ws + 205056;              // 8*409600 each
    float* Y1   = Y0 + (size_t)NIMG * IMG;
    float* E    = Y1 + (size_t)NIMG * IMG;
    float* G    = E  + (size_t)NIMG * IMG;
    float* U    = G  + (size_t)NIMG * IMG;

    prep_mats<<<1, 64, 0, stream>>>(P, mats);
    make_mask<<<NPAIR, 256, 0, stream>>>(mats, mask);
    rot_init<<<(NIMG * IMG + 255) / 256, 256, 0, stream>>>(x, Y0);

    float* yc = Y0;
    float* yn = Y1;
    for (int it = 0; it < 2; ++it) {
        // ego part: conv_e(y) + msg_b  (cin 64..127 of msg_w)
        conv_gen<1152><<<dim3(5, 5, NIMG * 4), 256, 0, stream>>>(
            yc, nullptr, msg_w + 64 * 9, msg_b, nullptr, E, 0);
        // agg = mean_i mask_i * (conv_n(warp_i(y)) + ego)
        msg_fused<<<dim3(5, 5, NIMG * 4), 256, 0, stream>>>(yc, E, mats, mask, msg_w, G);
        // update = sigmoid(conv([y|agg], gates_w[64:128, 0:128]) + gates_b[64:])
        conv_gen<1728><<<dim3(5, 5, NIMG * 4), 256, 0, stream>>>(
            yc, G, gates_w + (size_t)64 * 1728, gates_b + 64, nullptr, U, 1);
        // y_next = update * tanh(conv([y|agg], can_w[:, 0:128]) + can_b)
        conv_gen<1728><<<dim3(5, 5, NIMG * 4), 256, 0, stream>>>(
            yc, G, can_w, can_b, U, yn, 2);
        float* t = yc; yc = yn; yn = t;
    }

    final_mlp<<<(2 * HW * CH + 255) / 256, 256, 0, stream>>>(yc, mlp_w, mlp_b, out);
}

// Round 2
// 552.706 us; speedup vs baseline: 5.2187x; 5.2187x over previous
//
#include <hip/hip_runtime.h>
#include <math.h>

#define WD 80
#define HW 6400
#define CH 64
#define NIMG 8
#define NPAIR 32

typedef short bf16x8 __attribute__((ext_vector_type(8)));
typedef float f32x4 __attribute__((ext_vector_type(4)));

__device__ __forceinline__ float bf2f(unsigned short u) {
    return __uint_as_float(((unsigned)u) << 16);
}
__device__ __forceinline__ unsigned short f2bf(float f) {
    unsigned u = __float_as_uint(f);
    u += 0x7fff + ((u >> 16) & 1);          // RNE
    return (unsigned short)(u >> 16);
}

// ---------------- transformation matrices (inverse affine) ----------------
__global__ void prep_mats(const float* __restrict__ P, float* __restrict__ mats) {
    int p = threadIdx.x;
    if (p >= NPAIR) return;
    const float* m = P + p * 16;
    float m00 = m[0], m01 = m[1], m02 = m[3] / 0.8f;
    float m10 = m[4], m11 = m[5], m12 = m[7] / 0.8f;
    float cx = 40.0f, cy = 40.0f;
    float tx = cx - (m00 * cx + m01 * cy) + m02;
    float ty = cy - (m10 * cx + m11 * cy) + m12;
    float det = m00 * m11 - m01 * m10;
    float id = 1.0f / det;
    float a00 =  m11 * id, a01 = -m01 * id;
    float a10 = -m10 * id, a11 =  m00 * id;
    float a02 = -(a00 * tx + a01 * ty);
    float a12 = -(a10 * tx + a11 * ty);
    float* o = mats + p * 6;
    o[0] = a00; o[1] = a01; o[2] = a02;
    o[3] = a10; o[4] = a11; o[5] = a12;
}

// ---------------- nearest-neighbor validity mask ----------------
__global__ void make_mask(const float* __restrict__ mats, float* __restrict__ mask) {
    int p = blockIdx.x;
    const float* a = mats + p * 6;
    float a0 = a[0], a1 = a[1], a2 = a[2], a3 = a[3], a4 = a[4], a5 = a[5];
    for (int q = threadIdx.x; q < HW; q += blockDim.x) {
        float x = (float)(q % WD), y = (float)(q / WD);
        float sx = a0 * x + a1 * y + a2;
        float sy = a3 * x + a4 * y + a5;
        int ix = (int)rintf(sx), iy = (int)rintf(sy);
        mask[p * HW + q] = (ix >= 0 && ix < WD && iy >= 0 && iy < WD) ? 1.0f : 0.0f;
    }
}

// ---------------- initial rotation + CHW->HWC + fp32->bf16 ----------------
// Y[img][a][b][c] = x[img][c][79-b][a]
__global__ void rot_init_hwc(const float* __restrict__ x, unsigned short* __restrict__ y) {
    int t = blockIdx.x * blockDim.x + threadIdx.x;
    if (t >= NIMG * HW * CH) return;
    int c  = t & 63;
    int pb = (t >> 6) % WD;
    int pa = ((t >> 6) / WD) % WD;
    int img = t / (HW * CH);
    y[t] = f2bf(x[(size_t)(img * CH + c) * HW + (WD - 1 - pb) * WD + pa]);
}

// ---------------- weight repack: dst[tap][co][cin] bf16 ----------------
__global__ void prep_w(const float* __restrict__ src, unsigned short* __restrict__ dst,
                       int cin_n, int co_off, int ci_off, int co_stride) {
    int t = blockIdx.x * blockDim.x + threadIdx.x;
    if (t >= 9 * 64 * cin_n) return;
    int ci = t % cin_n;
    int co = (t / cin_n) & 63;
    int tap = t / (cin_n * 64);
    dst[t] = f2bf(src[(size_t)(co_off + co) * co_stride + (ci_off + ci) * 9 + tap]);
}

// ---------------- MFMA implicit-GEMM 3x3 conv ----------------
// grid (5,10,8): tile 16px(x) x 8rows(y), all 64 co. 256 thr = 4 waves,
// wave = 2 rows x 4 co-groups. LDS halo tile 10x18x64 bf16, XOR-swizzled 16B granules.
// MODE 0: out f32 = acc + bias.  MODE 1: out bf16 = sigmoid(acc+bias).
// MODE 2: out bf16 = mul * tanh(acc+bias).
template<int CIN, int MODE>
__global__ __launch_bounds__(256) void conv_mfma(
    const unsigned short* __restrict__ in0,
    const unsigned short* __restrict__ in1,
    const unsigned short* __restrict__ W,      // [9][64][CIN]
    const float* __restrict__ bias,            // [64]
    const unsigned short* __restrict__ mul,    // MODE 2 only
    void* __restrict__ outp) {
    __shared__ uint4 lds[1440];
    const int tid = threadIdx.x;
    const int lane = tid & 63;
    const int wv = tid >> 6;
    const int ll = lane & 15, lh = lane >> 4;
    const int x0 = blockIdx.x * 16, y0 = blockIdx.y * 8;
    const int img = blockIdx.z;

    f32x4 acc[2][4];
#pragma unroll
    for (int r = 0; r < 2; ++r)
#pragma unroll
        for (int cg = 0; cg < 4; ++cg) acc[r][cg] = (f32x4){0.f, 0.f, 0.f, 0.f};

    const int npass = CIN / 64;
    for (int pass = 0; pass < npass; ++pass) {
        const unsigned short* src = (pass == 0 ? in0 : in1) + (size_t)img * HW * CH;
        if (pass) __syncthreads();
        for (int idx = tid; idx < 1440; idx += 256) {
            int q = idx >> 3, g = idx & 7;
            int yl = q / 18, xl = q - yl * 18;
            int gy = y0 - 1 + yl, gx = x0 - 1 + xl;
            uint4 v = {0, 0, 0, 0};
            if ((unsigned)gx < WD && (unsigned)gy < WD)
                v = *(const uint4*)(src + ((gy * WD + gx) * 64 + g * 8));
            lds[q * 8 + (g ^ (q & 7))] = v;
        }
        __syncthreads();
#pragma unroll
        for (int tap = 0; tap < 9; ++tap) {
            const int ty = tap / 3, tx = tap % 3;
#pragma unroll
            for (int ks = 0; ks < 2; ++ks) {
                const unsigned short* wb = W + ((size_t)tap * 64 + ll) * CIN + pass * 64 + ks * 32 + lh * 8;
                bf16x8 Bf[4];
#pragma unroll
                for (int cg = 0; cg < 4; ++cg)
                    Bf[cg] = *(const bf16x8*)(wb + (size_t)cg * 16 * CIN);
#pragma unroll
                for (int r = 0; r < 2; ++r) {
                    int q = (2 * wv + r + ty) * 18 + tx + ll;
                    int g = ks * 4 + lh;
                    bf16x8 Af = *(const bf16x8*)&lds[q * 8 + (g ^ (q & 7))];
#pragma unroll
                    for (int cg = 0; cg < 4; ++cg)
                        acc[r][cg] = __builtin_amdgcn_mfma_f32_16x16x32_bf16(Af, Bf[cg], acc[r][cg], 0, 0, 0);
                }
            }
        }
    }
#pragma unroll
    for (int r = 0; r < 2; ++r) {
        int y = y0 + 2 * wv + r;
#pragma unroll
        for (int cg = 0; cg < 4; ++cg) {
            int co = cg * 16 + ll;
            float bv = bias[co];
#pragma unroll
            for (int j = 0; j < 4; ++j) {
                int x = x0 + lh * 4 + j;
                float v = acc[r][cg][j] + bv;
                size_t o = ((size_t)img * HW + y * WD + x) * 64 + co;
                if (MODE == 0) ((float*)outp)[o] = v;
                else if (MODE == 1) ((unsigned short*)outp)[o] = f2bf(1.f / (1.f + expf(-v)));
                else ((unsigned short*)outp)[o] = f2bf(bf2f(mul[o]) * tanhf(v));
            }
        }
    }
}

// ---------------- fused: bilinear warp + MFMA conv_n + mask + mean ----------------
__global__ __launch_bounds__(256) void msg_mfma(
    const unsigned short* __restrict__ Y,
    const float* __restrict__ E,        // f32 ego conv + bias, HWC
    const float* __restrict__ mats,
    const float* __restrict__ mask,
    const unsigned short* __restrict__ W,   // Wn [9][64][64]
    unsigned short* __restrict__ G) {
    __shared__ uint4 lds[1440];
    __shared__ int flag;
    const int tid = threadIdx.x;
    const int lane = tid & 63;
    const int wv = tid >> 6;
    const int ll = lane & 15, lh = lane >> 4;
    const int x0 = blockIdx.x * 16, y0 = blockIdx.y * 8;
    const int bj = blockIdx.z;
    const int b = bj >> 2, j = bj & 3;

    f32x4 tot[2][4];
    f32x4 msum[2];
#pragma unroll
    for (int r = 0; r < 2; ++r) {
        msum[r] = (f32x4){0.f, 0.f, 0.f, 0.f};
#pragma unroll
        for (int cg = 0; cg < 4; ++cg) tot[r][cg] = (f32x4){0.f, 0.f, 0.f, 0.f};
    }

    for (int i = 0; i < 4; ++i) {
        int p = (b * 4 + i) * 4 + j;
        const float* mk = mask + (size_t)p * HW;
        if (tid == 0) flag = 0;
        __syncthreads();
        if (tid < 128) {
            int yy = y0 + (tid >> 4), xx = x0 + (tid & 15);
            if (mk[yy * WD + xx] != 0.f) flag = 1;
        }
        __syncthreads();
        if (!flag) continue;

        const float* a = mats + p * 6;
        float a0 = a[0], a1 = a[1], a2 = a[2], a3 = a[3], a4 = a[4], a5 = a[5];
        const unsigned short* src = Y + (size_t)(b * 4 + i) * HW * CH;
        for (int idx = tid; idx < 1440; idx += 256) {
            int q = idx >> 3, g = idx & 7;
            int yl = q / 18, xl = q - yl * 18;
            int gy = y0 - 1 + yl, gx = x0 - 1 + xl;
            uint4 v = {0, 0, 0, 0};
            if ((unsigned)gx < WD && (unsigned)gy < WD) {
                float sx = a0 * gx + a1 * gy + a2;
                float sy = a3 * gx + a4 * gy + a5;
                float fxf = floorf(sx), fyf = floorf(sy);
                float fx = sx - fxf, fy = sy - fyf;
                int ix = (int)fxf, iy = (int)fyf;
                float w00 = (1.f - fx) * (1.f - fy), w10 = fx * (1.f - fy);
                float w01 = (1.f - fx) * fy,         w11 = fx * fy;
                bool vx0 = (unsigned)ix < WD, vx1 = (unsigned)(ix + 1) < WD;
                bool vy0 = (unsigned)iy < WD, vy1 = (unsigned)(iy + 1) < WD;
                if (!(vx0 && vy0)) w00 = 0.f;
                if (!(vx1 && vy0)) w10 = 0.f;
                if (!(vx0 && vy1)) w01 = 0.f;
                if (!(vx1 && vy1)) w11 = 0.f;
                int cx0 = min(max(ix, 0), WD - 1),     cx1 = min(max(ix + 1, 0), WD - 1);
                int cy0 = min(max(iy, 0), WD - 1),     cy1 = min(max(iy + 1, 0), WD - 1);
                uint4 c00 = *(const uint4*)(src + ((cy0 * WD + cx0) * 64 + g * 8));
                uint4 c10 = *(const uint4*)(src + ((cy0 * WD + cx1) * 64 + g * 8));
                uint4 c01 = *(const uint4*)(src + ((cy1 * WD + cx0) * 64 + g * 8));
                uint4 c11 = *(const uint4*)(src + ((cy1 * WD + cx1) * 64 + g * 8));
                const unsigned short* p00 = (const unsigned short*)&c00;
                const unsigned short* p10 = (const unsigned short*)&c10;
                const unsigned short* p01 = (const unsigned short*)&c01;
                const unsigned short* p11 = (const unsigned short*)&c11;
                unsigned short r8[8];
#pragma unroll
                for (int k = 0; k < 8; ++k) {
                    float vv = w00 * bf2f(p00[k]) + w10 * bf2f(p10[k])
                             + w01 * bf2f(p01[k]) + w11 * bf2f(p11[k]);
                    r8[k] = f2bf(vv);
                }
                v = *(const uint4*)r8;
            }
            lds[q * 8 + (g ^ (q & 7))] = v;
        }
        __syncthreads();

        f32x4 acc[2][4];
#pragma unroll
        for (int r = 0; r < 2; ++r)
#pragma unroll
            for (int cg = 0; cg < 4; ++cg) acc[r][cg] = (f32x4){0.f, 0.f, 0.f, 0.f};
#pragma unroll
        for (int tap = 0; tap < 9; ++tap) {
            const int ty = tap / 3, tx = tap % 3;
#pragma unroll
            for (int ks = 0; ks < 2; ++ks) {
                const unsigned short* wb = W + ((size_t)tap * 64 + ll) * 64 + ks * 32 + lh * 8;
                bf16x8 Bf[4];
#pragma unroll
                for (int cg = 0; cg < 4; ++cg)
                    Bf[cg] = *(const bf16x8*)(wb + (size_t)cg * 16 * 64);
#pragma unroll
                for (int r = 0; r < 2; ++r) {
                    int q = (2 * wv + r + ty) * 18 + tx + ll;
                    int g = ks * 4 + lh;
                    bf16x8 Af = *(const bf16x8*)&lds[q * 8 + (g ^ (q & 7))];
#pragma unroll
                    for (int cg = 0; cg < 4; ++cg)
                        acc[r][cg] = __builtin_amdgcn_mfma_f32_16x16x32_bf16(Af, Bf[cg], acc[r][cg], 0, 0, 0);
                }
            }
        }
        // fold with per-output-pixel mask
#pragma unroll
        for (int r = 0; r < 2; ++r) {
            int yy = y0 + 2 * wv + r;
#pragma unroll
            for (int jj = 0; jj < 4; ++jj) {
                int xx = x0 + lh * 4 + jj;
                float m = mk[yy * WD + xx];
                msum[r][jj] += m;
#pragma unroll
                for (int cg = 0; cg < 4; ++cg) tot[r][cg][jj] += m * acc[r][cg][jj];
            }
        }
    }
#pragma unroll
    for (int r = 0; r < 2; ++r) {
        int y = y0 + 2 * wv + r;
#pragma unroll
        for (int cg = 0; cg < 4; ++cg) {
            int co = cg * 16 + ll;
#pragma unroll
            for (int jj = 0; jj < 4; ++jj) {
                int x = x0 + lh * 4 + jj;
                size_t o = ((size_t)bj * HW + y * WD + x) * 64 + co;
                G[o] = f2bf(0.25f * (tot[r][cg][jj] + msum[r][jj] * E[o]));
            }
        }
    }
}

// ---------------- final: out[b,h,w,o] = sum_c Y[4b][w][79-h][c] * mlp_w[o,c] + mlp_b[o] ----------------
__global__ void final_mlp(const unsigned short* __restrict__ yfin, const float* __restrict__ mw,
                          const float* __restrict__ mb, float* __restrict__ out) {
    int t = blockIdx.x * blockDim.x + threadIdx.x;
    if (t >= 2 * HW * CH) return;
    int o  = t & 63;
    int wv = (t >> 6) % WD;
    int h  = ((t >> 6) / WD) % WD;
    int b  = t / (HW * CH);
    const unsigned short* src = yfin + ((size_t)(b * 4) * HW + wv * WD + (WD - 1 - h)) * 64;
    float r = mb[o];
#pragma unroll 8
    for (int c = 0; c < CH; ++c) r += bf2f(src[c]) * mw[o * CH + c];
    out[t] = r;
}

extern "C" void kernel_launch(void* const* d_in, const int* in_sizes, int n_in,
                              void* d_out, int out_size, void* d_ws, size_t ws_size,
                              hipStream_t stream) {
    const float* x       = (const float*)d_in[0];
    const float* P       = (const float*)d_in[2];
    const float* msg_w   = (const float*)d_in[4];
    const float* msg_b   = (const float*)d_in[5];
    const float* gates_w = (const float*)d_in[6];
    const float* gates_b = (const float*)d_in[7];
    const float* can_w   = (const float*)d_in[8];
    const float* can_b   = (const float*)d_in[9];
    const float* mlp_w   = (const float*)d_in[10];
    const float* mlp_b   = (const float*)d_in[11];
    float* out = (float*)d_out;

    char* wsb = (char*)d_ws;
    float* mats = (float*)wsb;                            // 768 B
    float* mask = (float*)(wsb + 1024);                   // 819200 B
    unsigned short* Wn = (unsigned short*)(wsb + 820224); // 73728 B
    unsigned short* We = Wn + 36864;                      // 73728 B
    unsigned short* Wu = We + 36864;                      // 147456 B
    unsigned short* Wc = Wu + 73728;                      // 147456 B
    unsigned short* Y0 = Wc + 73728;                      // 6553600 B
    unsigned short* Y1 = Y0 + 3276800;
    unsigned short* G  = Y1 + 3276800;
    unsigned short* U  = G  + 3276800;
    float* E = (float*)(U + 3276800);                     // 13107200 B

    prep_mats<<<1, 64, 0, stream>>>(P, mats);
    make_mask<<<NPAIR, 256, 0, stream>>>(mats, mask);
    rot_init_hwc<<<(NIMG * HW * CH + 255) / 256, 256, 0, stream>>>(x, Y0);
    prep_w<<<(9 * 64 * 64 + 255) / 256, 256, 0, stream>>>(msg_w, Wn, 64, 0, 0, 1152);
    prep_w<<<(9 * 64 * 64 + 255) / 256, 256, 0, stream>>>(msg_w, We, 64, 0, 64, 1152);
    prep_w<<<(9 * 64 * 128 + 255) / 256, 256, 0, stream>>>(gates_w, Wu, 128, 64, 0, 1728);
    prep_w<<<(9 * 64 * 128 + 255) / 256, 256, 0, stream>>>(can_w, Wc, 128, 0, 0, 1728);

    unsigned short* yc = Y0;
    unsigned short* yn = Y1;
    for (int it = 0; it < 2; ++it) {
        conv_mfma<64, 0><<<dim3(5, 10, NIMG), 256, 0, stream>>>(yc, nullptr, We, msg_b, nullptr, (void*)E);
        msg_mfma<<<dim3(5, 10, NIMG), 256, 0, stream>>>(yc, E, mats, mask, Wn, G);
        conv_mfma<128, 1><<<dim3(5, 10, NIMG), 256, 0, stream>>>(yc, G, Wu, gates_b + 64, nullptr, (void*)U);
        conv_mfma<128, 2><<<dim3(5, 10, NIMG), 256, 0, stream>>>(yc, G, Wc, can_b, U, (void*)yn);
        unsigned short* t = yc; yc = yn; yn = t;
    }
    final_mlp<<<(2 * HW * CH + 255) / 256, 256, 0, stream>>>(yc, mlp_w, mlp_b, out);
}